// Round 1
// baseline (27993.256 us; speedup 1.0000x reference)
//
#include <hip/hip_runtime.h>
#include <hip/hip_bf16.h>

// DA-RNN persistent kernel. Batch-parallel: each WG owns BB batch rows for the
// entire sequence (no cross-b coupling in the reference), so zero grid syncs.
// fp32 compute, bf16 scratch for ue_x / mid / ud_mid (needs 192 MiB of d_ws).

#define B_   1024
#define T_   128     // T_ENCO
#define NI_  128     // N_INP
#define H_   256     // N_HID
#define H4_  1024    // 4*N_HID
#define TD_  24      // T_DECO
#define DS_  30      // decoder steps
#define BB   4       // batch rows per workgroup
#define TB   512     // threads per block

__device__ __forceinline__ float sigm(float x) {
    return __builtin_amdgcn_rcpf(1.0f + __expf(-x));
}
__device__ __forceinline__ float tanh_f(float x) {
    // 1 - 2/(e^{2x}+1): exact limits at +-inf, no inf/inf NaN
    float e = __expf(2.0f * x);
    return 1.0f - 2.0f * __builtin_amdgcn_rcpf(e + 1.0f);
}
__device__ __forceinline__ float bf2f(unsigned short u) {
    union { unsigned int i; float f; } v; v.i = ((unsigned int)u) << 16; return v.f;
}
__device__ __forceinline__ unsigned short f2bf(float f) {
    union { float f; unsigned int i; } v; v.f = f;
    unsigned int r = v.i + 0x7fffu + ((v.i >> 16) & 1u);   // round-to-nearest-even
    return (unsigned short)(r >> 16);
}
__device__ __forceinline__ float fma4(float4 w, float4 x, float acc) {
    return fmaf(w.w, x.w, fmaf(w.z, x.z, fmaf(w.y, x.y, fmaf(w.x, x.x, acc))));
}

typedef unsigned short us8 __attribute__((ext_vector_type(8)));

__global__ __launch_bounds__(TB, 2) void dsrnn_kernel(
    const float* __restrict__ inp,
    const float* __restrict__ UeW,  const float* __restrict__ Ueb,
    const float* __restrict__ Ue2W, const float* __restrict__ Ue2b,
    const float* __restrict__ WeW,  const float* __restrict__ Web,
    const float* __restrict__ VeW,  const float* __restrict__ Veb,
    const float* __restrict__ UdW,  const float* __restrict__ Udb,
    const float* __restrict__ WdW,  const float* __restrict__ Wdb,
    const float* __restrict__ VdW,  const float* __restrict__ Vdb,
    const float* __restrict__ eWih, const float* __restrict__ eWhh,
    const float* __restrict__ ebih, const float* __restrict__ ebhh,
    const float* __restrict__ mWih, const float* __restrict__ mWhh,
    const float* __restrict__ mbih, const float* __restrict__ mbhh,
    const float* __restrict__ dWih, const float* __restrict__ dWhh,
    const float* __restrict__ dbih, const float* __restrict__ dbhh,
    const float* __restrict__ rW,   const float* __restrict__ rb,
    unsigned short* __restrict__ uex,    // (B,NI,H) bf16
    unsigned short* __restrict__ midb,   // (B,T,H)  bf16
    unsigned short* __restrict__ udm,    // (B,T,H)  bf16
    float* __restrict__ out)             // (B,TD) fp32
{
    __shared__ float sm[16384];   // 64 KiB; phase 0 uses all of it as X tile
    const int tid = threadIdx.x;
    const int b0  = blockIdx.x * BB;

    float* h_enc = sm;                 // [BB][H]   (decoder reuses as h_dec)
    float* c_enc = sm + 1024;          // [BB][H]
    float* h_mid = sm + 2048;          // [BB][H]
    float* c_mid = sm + 3072;          // [BB][H]
    float* xbuf  = sm + 4096;          // [BB][NI]
    float* hcxi  = sm + 4608;          // [BB][H]
    float* sbuf  = sm + 5632;          // [BB][NI]
    float* gbuf  = sm + 6144;          // [BB][H4]
    float* din   = sm + 10240;         // [BB][H]
    float* red   = sm + 11264;         // 8 floats softmax scratch

    // ---------------- Phase 0: ue_x[b,j,k] = sum_t X[t,j]*UeW[k,t] + Ueb[k] ----
    {
        const int k  = tid & 255;
        const int jh = tid >> 8;                 // j half: 0 or 1
        const float* wrow = UeW + (size_t)k * T_;
        const float biask = Ueb[k];
        for (int b = 0; b < BB; ++b) {
            __syncthreads();
            const float* Xg = inp + (size_t)(b0 + b) * T_ * NI_;
            for (int i = tid; i < T_ * NI_; i += TB) sm[i] = Xg[i];
            __syncthreads();
            unsigned short* ub = uex + (size_t)(b0 + b) * NI_ * H_;
            for (int j0 = jh * 64; j0 < jh * 64 + 64; j0 += 4) {
                float a0 = biask, a1 = biask, a2 = biask, a3 = biask;
                for (int t = 0; t < T_; ++t) {
                    float  w  = wrow[t];
                    float4 x4 = *(const float4*)&sm[t * NI_ + j0];
                    a0 = fmaf(w, x4.x, a0); a1 = fmaf(w, x4.y, a1);
                    a2 = fmaf(w, x4.z, a2); a3 = fmaf(w, x4.w, a3);
                }
                ub[(size_t)(j0 + 0) * H_ + k] = f2bf(a0);
                ub[(size_t)(j0 + 1) * H_ + k] = f2bf(a1);
                ub[(size_t)(j0 + 2) * H_ + k] = f2bf(a2);
                ub[(size_t)(j0 + 3) * H_ + k] = f2bf(a3);
            }
        }
    }
    __syncthreads();
    for (int i = tid; i < 4096; i += TB) sm[i] = 0.0f;   // h/c enc+mid = 0
    __syncthreads();

    // ---------------- Fused encoder + mid loop ----------------
    for (int t = 0; t < T_; ++t) {
        // (1) load x_t (raw)
        xbuf[tid] = inp[((size_t)(b0 + (tid >> 7)) * T_ + t) * NI_ + (tid & 127)];
        __syncthreads();

        // (2) hcxi = We.[h;c] + Web + Ue2.x + Ue2b   (thread: k, 2 batch rows)
        {
            const int k = tid & 255, bh = tid >> 8;
            const int bA = bh * 2, bC = bh * 2 + 1;
            const float* wr  = WeW  + (size_t)k * (2 * H_);
            const float* u2r = Ue2W + (size_t)k * NI_;
            float acc0 = Web[k] + Ue2b[k];
            float acc1 = acc0;
            for (int k2 = 0; k2 < H_; k2 += 4) {
                float4 w4 = *(const float4*)&wr[k2];
                acc0 = fma4(w4, *(const float4*)&h_enc[bA * H_ + k2], acc0);
                acc1 = fma4(w4, *(const float4*)&h_enc[bC * H_ + k2], acc1);
            }
            for (int k2 = 0; k2 < H_; k2 += 4) {
                float4 w4 = *(const float4*)&wr[H_ + k2];
                acc0 = fma4(w4, *(const float4*)&c_enc[bA * H_ + k2], acc0);
                acc1 = fma4(w4, *(const float4*)&c_enc[bC * H_ + k2], acc1);
            }
            for (int j = 0; j < NI_; j += 4) {
                float4 w4 = *(const float4*)&u2r[j];
                acc0 = fma4(w4, *(const float4*)&xbuf[bA * NI_ + j], acc0);
                acc1 = fma4(w4, *(const float4*)&xbuf[bC * NI_ + j], acc1);
            }
            hcxi[bA * H_ + k] = acc0;
            hcxi[bC * H_ + k] = acc1;
        }
        __syncthreads();

        // (3) scores s[b,j] = Veb + sum_k VeW[k]*tanh(hcxi[b,k] + uex[b,j,k])
        {
            const int b = tid >> 7, j = tid & 127;
            const us8* up = (const us8*)(uex + ((size_t)(b0 + b) * NI_ + j) * H_);
            float acc = Veb[0];
            for (int kc = 0; kc < H_ / 8; ++kc) {
                us8 u = up[kc];
#pragma unroll
                for (int e = 0; e < 8; ++e) {
                    float tv = tanh_f(hcxi[b * H_ + kc * 8 + e] + bf2f(u[e]));
                    acc = fmaf(VeW[kc * 8 + e], tv, acc);
                }
            }
            sbuf[tid] = acc;
        }
        __syncthreads();

        // (4) softmax over j (axis=1), then gate x in place
        if (tid < BB) {
            float mx = -3.4e38f;
            for (int j = 0; j < NI_; ++j) mx = fmaxf(mx, sbuf[tid * NI_ + j]);
            red[tid] = mx;
        }
        __syncthreads();
        sbuf[tid] = __expf(sbuf[tid] - red[tid >> 7]);
        __syncthreads();
        if (tid < BB) {
            float s = 0.0f;
            for (int j = 0; j < NI_; ++j) s += sbuf[tid * NI_ + j];
            red[4 + tid] = 1.0f / s;
        }
        __syncthreads();
        xbuf[tid] *= sbuf[tid] * red[4 + (tid >> 7)];
        __syncthreads();

        // (5) encoder gates: g = eWih.(x*a) + eWhh.h + biases  (thread: o, o+512, all b)
        {
            const int o = tid;
            const float* wi0 = eWih + (size_t)o * NI_;
            const float* wi1 = eWih + (size_t)(o + 512) * NI_;
            const float* wh0 = eWhh + (size_t)o * H_;
            const float* wh1 = eWhh + (size_t)(o + 512) * H_;
            float bias0 = ebih[o] + ebhh[o];
            float bias1 = ebih[o + 512] + ebhh[o + 512];
            float acc0[BB], acc1[BB];
#pragma unroll
            for (int b = 0; b < BB; ++b) { acc0[b] = bias0; acc1[b] = bias1; }
            for (int j = 0; j < NI_; j += 4) {
                float4 w0 = *(const float4*)&wi0[j];
                float4 w1 = *(const float4*)&wi1[j];
#pragma unroll
                for (int b = 0; b < BB; ++b) {
                    float4 x4 = *(const float4*)&xbuf[b * NI_ + j];
                    acc0[b] = fma4(w0, x4, acc0[b]);
                    acc1[b] = fma4(w1, x4, acc1[b]);
                }
            }
            for (int k = 0; k < H_; k += 4) {
                float4 w0 = *(const float4*)&wh0[k];
                float4 w1 = *(const float4*)&wh1[k];
#pragma unroll
                for (int b = 0; b < BB; ++b) {
                    float4 h4 = *(const float4*)&h_enc[b * H_ + k];
                    acc0[b] = fma4(w0, h4, acc0[b]);
                    acc1[b] = fma4(w1, h4, acc1[b]);
                }
            }
#pragma unroll
            for (int b = 0; b < BB; ++b) {
                gbuf[b * H4_ + o]       = acc0[b];
                gbuf[b * H4_ + o + 512] = acc1[b];
            }
        }
        __syncthreads();

        // (6) encoder LSTM update
        {
            const int k = tid & 255;
            for (int b = tid >> 8; b < BB; b += 2) {
                float ig = gbuf[b * H4_ + k];
                float fg = gbuf[b * H4_ + H_ + k];
                float gg = gbuf[b * H4_ + 2 * H_ + k];
                float og = gbuf[b * H4_ + 3 * H_ + k];
                float c2 = sigm(fg) * c_enc[b * H_ + k] + sigm(ig) * tanh_f(gg);
                float h2 = sigm(og) * tanh_f(c2);
                c_enc[b * H_ + k] = c2;
                h_enc[b * H_ + k] = h2;
            }
        }
        __syncthreads();

        // (7) mid gates: g = mWih.h_enc(new) + mWhh.h_mid + biases
        {
            const int o = tid;
            const float* wi0 = mWih + (size_t)o * H_;
            const float* wi1 = mWih + (size_t)(o + 512) * H_;
            const float* wh0 = mWhh + (size_t)o * H_;
            const float* wh1 = mWhh + (size_t)(o + 512) * H_;
            float bias0 = mbih[o] + mbhh[o];
            float bias1 = mbih[o + 512] + mbhh[o + 512];
            float acc0[BB], acc1[BB];
#pragma unroll
            for (int b = 0; b < BB; ++b) { acc0[b] = bias0; acc1[b] = bias1; }
            for (int k = 0; k < H_; k += 4) {
                float4 w0 = *(const float4*)&wi0[k];
                float4 w1 = *(const float4*)&wi1[k];
#pragma unroll
                for (int b = 0; b < BB; ++b) {
                    float4 h4 = *(const float4*)&h_enc[b * H_ + k];
                    acc0[b] = fma4(w0, h4, acc0[b]);
                    acc1[b] = fma4(w1, h4, acc1[b]);
                }
            }
            for (int k = 0; k < H_; k += 4) {
                float4 w0 = *(const float4*)&wh0[k];
                float4 w1 = *(const float4*)&wh1[k];
#pragma unroll
                for (int b = 0; b < BB; ++b) {
                    float4 h4 = *(const float4*)&h_mid[b * H_ + k];
                    acc0[b] = fma4(w0, h4, acc0[b]);
                    acc1[b] = fma4(w1, h4, acc1[b]);
                }
            }
#pragma unroll
            for (int b = 0; b < BB; ++b) {
                gbuf[b * H4_ + o]       = acc0[b];
                gbuf[b * H4_ + o + 512] = acc1[b];
            }
        }
        __syncthreads();

        // (8) mid LSTM update
        {
            const int k = tid & 255;
            for (int b = tid >> 8; b < BB; b += 2) {
                float ig = gbuf[b * H4_ + k];
                float fg = gbuf[b * H4_ + H_ + k];
                float gg = gbuf[b * H4_ + 2 * H_ + k];
                float og = gbuf[b * H4_ + 3 * H_ + k];
                float c2 = sigm(fg) * c_mid[b * H_ + k] + sigm(ig) * tanh_f(gg);
                float h2 = sigm(og) * tanh_f(c2);
                c_mid[b * H_ + k] = c2;
                h_mid[b * H_ + k] = h2;
            }
        }
        __syncthreads();

        // (9) store mid (bf16) and ud_mid = Ud.h_mid + Udb (bf16)
        {
            const int k = tid & 255, bh = tid >> 8;
            const float* ur = UdW + (size_t)k * H_;
            for (int b = bh; b < BB; b += 2) {
                float hm = h_mid[b * H_ + k];
                midb[((size_t)(b0 + b) * T_ + t) * H_ + k] = f2bf(hm);
                float acc = Udb[k];
                for (int k2 = 0; k2 < H_; k2 += 4) {
                    float4 w4 = *(const float4*)&ur[k2];
                    acc = fma4(w4, *(const float4*)&h_mid[b * H_ + k2], acc);
                }
                udm[((size_t)(b0 + b) * T_ + t) * H_ + k] = f2bf(acc);
            }
        }
        __syncthreads();
    }

    // ---------------- Decoder ----------------
    for (int i = tid; i < 2048; i += TB) sm[i] = 0.0f;   // h_dec, c_dec = 0
    __syncthreads();

    for (int s = 0; s < DS_; ++s) {
        // wd = Wd.[h;c] + Wdb  -> hcxi
        {
            const int k = tid & 255, bh = tid >> 8;
            const int bA = bh * 2, bC = bh * 2 + 1;
            const float* wr = WdW + (size_t)k * (2 * H_);
            float acc0 = Wdb[k], acc1 = Wdb[k];
            for (int k2 = 0; k2 < H_; k2 += 4) {
                float4 w4 = *(const float4*)&wr[k2];
                acc0 = fma4(w4, *(const float4*)&h_enc[bA * H_ + k2], acc0);
                acc1 = fma4(w4, *(const float4*)&h_enc[bC * H_ + k2], acc1);
            }
            for (int k2 = 0; k2 < H_; k2 += 4) {
                float4 w4 = *(const float4*)&wr[H_ + k2];
                acc0 = fma4(w4, *(const float4*)&c_enc[bA * H_ + k2], acc0);
                acc1 = fma4(w4, *(const float4*)&c_enc[bC * H_ + k2], acc1);
            }
            hcxi[bA * H_ + k] = acc0;
            hcxi[bC * H_ + k] = acc1;
        }
        __syncthreads();

        // t_score[b,j] = Vdb + sum_k VdW[k]*tanh(wd[b,k] + ud_mid[b,j,k])  (NO softmax)
        {
            const int b = tid >> 7, j = tid & 127;
            const us8* up = (const us8*)(udm + ((size_t)(b0 + b) * T_ + j) * H_);
            float acc = Vdb[0];
            for (int kc = 0; kc < H_ / 8; ++kc) {
                us8 u = up[kc];
#pragma unroll
                for (int e = 0; e < 8; ++e) {
                    float tv = tanh_f(hcxi[b * H_ + kc * 8 + e] + bf2f(u[e]));
                    acc = fmaf(VdW[kc * 8 + e], tv, acc);
                }
            }
            sbuf[tid] = acc;
        }
        __syncthreads();

        // dec_in[b,h] = sum_j t[b,j] * mid[b,j,h]
        {
            const int h = tid & 255, bh = tid >> 8;
            for (int b = bh; b < BB; b += 2) {
                const unsigned short* mrow = midb + (size_t)(b0 + b) * T_ * H_ + h;
                float acc = 0.0f;
                for (int j = 0; j < T_; ++j)
                    acc = fmaf(sbuf[b * NI_ + j], bf2f(mrow[(size_t)j * H_]), acc);
                din[b * H_ + h] = acc;
            }
        }
        __syncthreads();

        // dec gates: g = dWih.dec_in + dWhh.h + biases
        {
            const int o = tid;
            const float* wi0 = dWih + (size_t)o * H_;
            const float* wi1 = dWih + (size_t)(o + 512) * H_;
            const float* wh0 = dWhh + (size_t)o * H_;
            const float* wh1 = dWhh + (size_t)(o + 512) * H_;
            float bias0 = dbih[o] + dbhh[o];
            float bias1 = dbih[o + 512] + dbhh[o + 512];
            float acc0[BB], acc1[BB];
#pragma unroll
            for (int b = 0; b < BB; ++b) { acc0[b] = bias0; acc1[b] = bias1; }
            for (int k = 0; k < H_; k += 4) {
                float4 w0 = *(const float4*)&wi0[k];
                float4 w1 = *(const float4*)&wi1[k];
#pragma unroll
                for (int b = 0; b < BB; ++b) {
                    float4 x4 = *(const float4*)&din[b * H_ + k];
                    acc0[b] = fma4(w0, x4, acc0[b]);
                    acc1[b] = fma4(w1, x4, acc1[b]);
                }
            }
            for (int k = 0; k < H_; k += 4) {
                float4 w0 = *(const float4*)&wh0[k];
                float4 w1 = *(const float4*)&wh1[k];
#pragma unroll
                for (int b = 0; b < BB; ++b) {
                    float4 h4 = *(const float4*)&h_enc[b * H_ + k];
                    acc0[b] = fma4(w0, h4, acc0[b]);
                    acc1[b] = fma4(w1, h4, acc1[b]);
                }
            }
#pragma unroll
            for (int b = 0; b < BB; ++b) {
                gbuf[b * H4_ + o]       = acc0[b];
                gbuf[b * H4_ + o + 512] = acc1[b];
            }
        }
        __syncthreads();

        // dec LSTM update (state in h_enc/c_enc buffers)
        {
            const int k = tid & 255;
            for (int b = tid >> 8; b < BB; b += 2) {
                float ig = gbuf[b * H4_ + k];
                float fg = gbuf[b * H4_ + H_ + k];
                float gg = gbuf[b * H4_ + 2 * H_ + k];
                float og = gbuf[b * H4_ + 3 * H_ + k];
                float c2 = sigm(fg) * c_enc[b * H_ + k] + sigm(ig) * tanh_f(gg);
                float h2 = sigm(og) * tanh_f(c2);
                c_enc[b * H_ + k] = c2;
                h_enc[b * H_ + k] = h2;
            }
        }
        __syncthreads();

        // output: out[b, s-6] = rW.h + rb  for s >= 6
        if (s >= 6 && tid < BB) {
            float acc = rb[0];
            for (int k = 0; k < H_; k += 4)
                acc = fma4(*(const float4*)&rW[k], *(const float4*)&h_enc[tid * H_ + k], acc);
            out[(size_t)(b0 + tid) * TD_ + (s - 6)] = acc;
        }
        __syncthreads();
    }
}

extern "C" void kernel_launch(void* const* d_in, const int* in_sizes, int n_in,
                              void* d_out, int out_size, void* d_ws, size_t ws_size,
                              hipStream_t stream) {
    const float* inp  = (const float*)d_in[0];
    // d_in[1] = label_p (unused by the reference output)
    const float* UeW  = (const float*)d_in[2];
    const float* Ueb  = (const float*)d_in[3];
    const float* Ue2W = (const float*)d_in[4];
    const float* Ue2b = (const float*)d_in[5];
    const float* WeW  = (const float*)d_in[6];
    const float* Web  = (const float*)d_in[7];
    const float* VeW  = (const float*)d_in[8];
    const float* Veb  = (const float*)d_in[9];
    const float* UdW  = (const float*)d_in[10];
    const float* Udb  = (const float*)d_in[11];
    const float* WdW  = (const float*)d_in[12];
    const float* Wdb  = (const float*)d_in[13];
    const float* VdW  = (const float*)d_in[14];
    const float* Vdb  = (const float*)d_in[15];
    const float* eWih = (const float*)d_in[16];
    const float* eWhh = (const float*)d_in[17];
    const float* ebih = (const float*)d_in[18];
    const float* ebhh = (const float*)d_in[19];
    const float* mWih = (const float*)d_in[20];
    const float* mWhh = (const float*)d_in[21];
    const float* mbih = (const float*)d_in[22];
    const float* mbhh = (const float*)d_in[23];
    const float* dWih = (const float*)d_in[24];
    const float* dWhh = (const float*)d_in[25];
    const float* dbih = (const float*)d_in[26];
    const float* dbhh = (const float*)d_in[27];
    const float* rW   = (const float*)d_in[28];
    const float* rb   = (const float*)d_in[29];

    // workspace: three (B,128,256) bf16 tensors = 192 MiB total
    unsigned short* uex  = (unsigned short*)d_ws;
    unsigned short* midb = uex  + (size_t)B_ * NI_ * H_;
    unsigned short* udm  = midb + (size_t)B_ * T_  * H_;

    dsrnn_kernel<<<B_ / BB, TB, 0, stream>>>(
        inp, UeW, Ueb, Ue2W, Ue2b, WeW, Web, VeW, Veb,
        UdW, Udb, WdW, Wdb, VdW, Vdb,
        eWih, eWhh, ebih, ebhh, mWih, mWhh, mbih, mbhh,
        dWih, dWhh, dbih, dbhh, rW, rb,
        uex, midb, udm, (float*)d_out);
}